// Round 7
// baseline (401.260 us; speedup 1.0000x reference)
//
#include <hip/hip_runtime.h>
#include <hip/hip_bf16.h>

static constexpr int HEADS = 4;
static constexpr int HID   = 64;
static constexpr int HC    = 256;   // HEADS*HID
static constexpr int NCLS  = 10;

typedef short    bf16x8 __attribute__((ext_vector_type(8)));
typedef _Float16 f16x8  __attribute__((ext_vector_type(8)));
typedef _Float16 f16x4  __attribute__((ext_vector_type(4)));
typedef float    f32x4  __attribute__((ext_vector_type(4)));

__device__ inline unsigned short f2bf(float f) {
    union { float f; unsigned u; } c; c.f = f;
    unsigned r = (c.u + 0x7fff + ((c.u >> 16) & 1)) >> 16;  // RNE
    return (unsigned short)r;
}
__device__ inline unsigned short f2h(float f) {
    _Float16 h = (_Float16)f; unsigned short u; __builtin_memcpy(&u, &h, 2); return u;
}
__device__ inline float h2f(unsigned short u) {
    _Float16 h; __builtin_memcpy(&h, &u, 2); return (float)h;
}

// ------------------------------------------------------------------ prep ----
// b=0: cE + qctr reset; b=1..256: Wt[n][k]=bf16(W[k][n]); b=257..272: fcWh
__global__ void prep_kernel(const float* __restrict__ We, const float* __restrict__ attE,
                            float* __restrict__ cE, const float* __restrict__ W,
                            unsigned short* __restrict__ Wt, const float* __restrict__ fcW,
                            unsigned short* __restrict__ fcWh, int* __restrict__ qctr) {
    int b = blockIdx.x, t = threadIdx.x;
    if (b == 0) {
        if (t == 0) qctr[0] = 0;
        float p = We[t] * attE[t];
#pragma unroll
        for (int d = 32; d; d >>= 1) p += __shfl_xor(p, d, 64);
        if ((t & 63) == 0) cE[t >> 6] = p;
    } else if (b <= 256) {
        int k = b - 1;
        Wt[t * 256 + k] = f2bf(W[k * 256 + t]);
    } else {
        int j = b - 257;               // 0..15
        unsigned short v = 0;
        if (j < NCLS) v = f2h(fcW[t * NCLS + j]);
        fcWh[j * 256 + t] = v;
    }
}

// ------------------------------------------------------------ MFMA GEMM -----
// XHh[M,256](f16) = X[M,256](f32) @ Wt^T (bf16 MFMA).
__global__ __launch_bounds__(256) void gemm_mfma(const float* __restrict__ X,
                                                 const unsigned short* __restrict__ Bt,
                                                 unsigned short* __restrict__ XHh, int M) {
    __shared__ alignas(16) unsigned short As[128][40];
    __shared__ alignas(16) unsigned short Bs[128][40];  // Bs[col][k]
    const int tid = threadIdx.x;
    const int lane = tid & 63, wid = tid >> 6;
    const int wr = wid >> 1, wc = wid & 1;
    const int bm = blockIdx.x * 128, bn = blockIdx.y * 128;
    const int fr = lane & 15, kg = lane >> 4;

    f32x4 acc[4][4] = {};

    for (int k0 = 0; k0 < 256; k0 += 32) {
        __syncthreads();
#pragma unroll
        for (int ss = 0; ss < 4; ++ss) {
            int idx = tid + (ss << 8);
            int row = idx >> 3, seg = idx & 7;
            int grow = bm + row;
            float4 av = make_float4(0.f, 0.f, 0.f, 0.f);
            if (grow < M) av = *(const float4*)&X[(size_t)grow * 256 + k0 + seg * 4];
            ushort4 ab = make_ushort4(f2bf(av.x), f2bf(av.y), f2bf(av.z), f2bf(av.w));
            *(ushort4*)&As[row][seg * 4] = ab;
        }
#pragma unroll
        for (int qq = 0; qq < 2; ++qq) {
            int q = tid + (qq << 8);
            int row = q >> 2, part = q & 3;
            const ushort4* bp = (const ushort4*)&Bt[(size_t)(bn + row) * 256 + k0 + part * 8];
            *(ushort4*)&Bs[row][part * 8]     = bp[0];
            *(ushort4*)&Bs[row][part * 8 + 4] = bp[1];
        }
        __syncthreads();

        bf16x8 af[4], bf[4];
#pragma unroll
        for (int i = 0; i < 4; ++i)
            af[i] = *(const bf16x8*)&As[wr * 64 + i * 16 + fr][kg * 8];
#pragma unroll
        for (int j = 0; j < 4; ++j)
            bf[j] = *(const bf16x8*)&Bs[wc * 64 + j * 16 + fr][kg * 8];
#pragma unroll
        for (int i = 0; i < 4; ++i)
#pragma unroll
            for (int j = 0; j < 4; ++j)
                acc[i][j] = __builtin_amdgcn_mfma_f32_16x16x32_bf16(af[i], bf[j], acc[i][j], 0, 0, 0);
    }

    // C/D layout: col = lane&15, row = (lane>>4)*4 + reg
#pragma unroll
    for (int i = 0; i < 4; ++i) {
#pragma unroll
        for (int j = 0; j < 4; ++j) {
            int col = bn + wc * 64 + j * 16 + fr;
#pragma unroll
            for (int r = 0; r < 4; ++r) {
                int row = bm + wr * 64 + i * 16 + kg * 4 + r;
                if (row < M) XHh[(size_t)row * 256 + col] = f2h(acc[i][j][r]);
            }
        }
    }
}

// ------------------------------------------------------- a_src / a_dst ------
__global__ __launch_bounds__(256) void attn_coef(const unsigned short* __restrict__ xhh,
                                                 const float* __restrict__ attS,
                                                 const float* __restrict__ attD,
                                                 float* __restrict__ a_src,
                                                 float* __restrict__ a_dst,
                                                 int Nn) {
    int wid = threadIdx.x >> 6, lane = threadIdx.x & 63;
    int n = blockIdx.x * 4 + wid;
    if (n >= Nn) return;
    ushort4 xv = *(const ushort4*)&xhh[(size_t)n * HC + lane * 4];
    float x0 = h2f(xv.x), x1 = h2f(xv.y), x2 = h2f(xv.z), x3 = h2f(xv.w);
    float4 sv = *(const float4*)&attS[lane * 4];
    float4 dv = *(const float4*)&attD[lane * 4];
    float ps = x0 * sv.x + x1 * sv.y + x2 * sv.z + x3 * sv.w;
    float pd = x0 * dv.x + x1 * dv.y + x2 * dv.z + x3 * dv.w;
#pragma unroll
    for (int d = 1; d < 16; d <<= 1) {
        ps += __shfl_xor(ps, d, 64);
        pd += __shfl_xor(pd, d, 64);
    }
    if ((lane & 15) == 0) {
        a_src[n * 4 + (lane >> 4)] = ps;
        a_dst[n * 4 + (lane >> 4)] = pd;
    }
}

// ------------------------------------------------------------- CSR build ----
__global__ void hist_kernel(const int* __restrict__ dst, int* __restrict__ deg,
                            int* __restrict__ rank, int E) {
    int e = blockIdx.x * 256 + threadIdx.x;
    if (e < E) rank[e] = atomicAdd(&deg[dst[e]], 1);
}

// scan of PADDED degrees (each deg rounded up to x4)
__global__ __launch_bounds__(1024) void scan1(const int* __restrict__ deg,
                                              int* __restrict__ row_start,
                                              int* __restrict__ bsum, int n) {
    __shared__ int wsum[16];
    const int tid = threadIdx.x, lane = tid & 63, wid = tid >> 6;
    int i = blockIdx.x * 1024 + tid;
    int v = (i < n) ? ((deg[i] + 3) & ~3) : 0;
    int incl = v;
#pragma unroll
    for (int d = 1; d < 64; d <<= 1) {
        int t = __shfl_up(incl, d, 64);
        if (lane >= d) incl += t;
    }
    if (lane == 63) wsum[wid] = incl;
    __syncthreads();
    if (tid < 16) {
        int w = wsum[tid];
#pragma unroll
        for (int d = 1; d < 16; d <<= 1) {
            int t = __shfl_up(w, d, 16);
            if (tid >= d) w += t;
        }
        wsum[tid] = w;
    }
    __syncthreads();
    int waveoff = wid ? wsum[wid - 1] : 0;
    if (i < n) row_start[i] = waveoff + incl - v;
    if (tid == 1023) bsum[blockIdx.x] = waveoff + incl;
}

// fused scan2+scan3 + pad-slot zeroing (pads read as src=0, p=0 downstream)
__global__ __launch_bounds__(1024) void scan23(int* __restrict__ row_start,
                                               const int* __restrict__ bsum,
                                               const int* __restrict__ deg,
                                               int* __restrict__ srcs,
                                               float* __restrict__ pq, int n, int nb) {
    __shared__ int pref[64];
    const int tid = threadIdx.x;
    if (tid < 64) {
        int v = (tid < nb) ? bsum[tid] : 0;
#pragma unroll
        for (int d = 1; d < 64; d <<= 1) {
            int t = __shfl_up(v, d, 64);
            if (tid >= d) v += t;
        }
        pref[tid] = v;
    }
    __syncthreads();
    int add = blockIdx.x ? pref[blockIdx.x - 1] : 0;
    int i = blockIdx.x * 1024 + tid;
    if (i < n) {
        int v = row_start[i] + add;
        row_start[i] = v;
        int dn = deg[i];
        int pd = (dn + 3) & ~3;
        for (int s = dn; s < pd; ++s) {       // <=3 pad slots
            int pos = v + s;
            srcs[pos] = 0;
            float* b = pq + (size_t)(pos >> 2) * 16 + (pos & 3);
            b[0] = 0.f; b[4] = 0.f; b[8] = 0.f; b[12] = 0.f;
        }
    }
    if (i == n) row_start[n] = pref[nb - 1];
}

// ------------------------------------------------------------ scatter+p -----
// pos = row_start[dst] + rank  (no atomics). p layout: pq[group][h][4].
__global__ void scatter_p(const int* __restrict__ src, const int* __restrict__ dst,
                          const float* __restrict__ ew, const float* __restrict__ a_src,
                          const float* __restrict__ a_dst, const float* __restrict__ cE,
                          const int* __restrict__ row_start, const int* __restrict__ rank,
                          int* __restrict__ srcs, float* __restrict__ pq, int E) {
    int e = blockIdx.x * 256 + threadIdx.x;
    if (e >= E) return;
    int s = src[e], d = dst[e];
    float w = ew[e];
    float4 as_ = *(const float4*)&a_src[s * 4];
    float4 ad_ = *(const float4*)&a_dst[d * 4];
    float4 ce  = *(const float4*)cE;
    int pos = row_start[d] + rank[e];
    srcs[pos] = s;
    float al[4] = {as_.x + ad_.x + ce.x * w, as_.y + ad_.y + ce.y * w,
                   as_.z + ad_.z + ce.z * w, as_.w + ad_.w + ce.w * w};
    float* base = pq + ((size_t)(pos >> 2)) * 16 + (pos & 3);
#pragma unroll
    for (int h = 0; h < 4; ++h) {
        float a = al[h] > 0.f ? al[h] : 0.2f * al[h];
        base[h * 4] = __expf(a);           // no max-sub: |alpha| small
    }
}

// ------------------------------------------------------------- main GAT -----
// Persistent waves + atomic work queue (4 nodes per pop). One wave per node;
// lane owns channels 4l..4l+3. Unroll-4 rotation software pipeline: compute
// chunk c, gathers for c+1 in flight, meta prefetched to c+(4..7). All chunks
// full (pads pre-zeroed by scan23). Scalar (SGPR) addressing: node index via
// readfirstlane -> srcs meta s_load -> gather bases in SGPRs, 0 VALU addr.
__global__ __launch_bounds__(256) void gat_main(
    const unsigned short* __restrict__ xhh, const int* __restrict__ row_start,
    const int* __restrict__ srcs, const float* __restrict__ pq,
    const float* __restrict__ bias, const float* __restrict__ gamma,
    const float* __restrict__ beta, unsigned short* __restrict__ yh,
    int* __restrict__ qctr, int Nn) {
    const int lane = threadIdx.x & 63;
    const int myh4 = (lane >> 4) << 2;     // head*4 (float offset into group rec)

    const float4 bv  = *(const float4*)&bias[lane * 4];
    const float4 gv  = *(const float4*)&gamma[lane * 4];
    const float4 btv = *(const float4*)&beta[lane * 4];

#define META(S, P, c_) do {                                                    \
    S = *(const int4*)(srcs + (size_t)(rs4 + (c_)) * 4);                       \
    P = *(const float4*)(pq + (size_t)(rs4 + (c_)) * 16 + myh4);               \
} while (0)
#define GAT1(A, t_) do {                                                       \
    int t = (t_);                                                              \
    if ((unsigned)t >= (unsigned)Nn) t = 0;                                    \
    A = ((const f16x4*)(xhh + (size_t)t * HC))[lane];                          \
} while (0)
#define GATH(A0, A1, A2, A3, S) do {                                           \
    GAT1(A0, (S).x); GAT1(A1, (S).y); GAT1(A2, (S).z); GAT1(A3, (S).w);        \
} while (0)
#define COMP(P, A0, A1, A2, A3) do {                                           \
    psum += ((P).x + (P).y) + ((P).z + (P).w);                                 \
    acc[0] = fmaf((P).x, (float)(A0).x, acc[0]);                               \
    acc[1] = fmaf((P).x, (float)(A0).y, acc[1]);                               \
    acc[2] = fmaf((P).x, (float)(A0).z, acc[2]);                               \
    acc[3] = fmaf((P).x, (float)(A0).w, acc[3]);                               \
    acc[0] = fmaf((P).y, (float)(A1).x, acc[0]);                               \
    acc[1] = fmaf((P).y, (float)(A1).y, acc[1]);                               \
    acc[2] = fmaf((P).y, (float)(A1).z, acc[2]);                               \
    acc[3] = fmaf((P).y, (float)(A1).w, acc[3]);                               \
    acc[0] = fmaf((P).z, (float)(A2).x, acc[0]);                               \
    acc[1] = fmaf((P).z, (float)(A2).y, acc[1]);                               \
    acc[2] = fmaf((P).z, (float)(A2).z, acc[2]);                               \
    acc[3] = fmaf((P).z, (float)(A2).w, acc[3]);                               \
    acc[0] = fmaf((P).w, (float)(A3).x, acc[0]);                               \
    acc[1] = fmaf((P).w, (float)(A3).y, acc[1]);                               \
    acc[2] = fmaf((P).w, (float)(A3).z, acc[2]);                               \
    acc[3] = fmaf((P).w, (float)(A3).w, acc[3]);                               \
} while (0)

    for (;;) {
        int pop0 = 0;
        if (lane == 0) pop0 = atomicAdd(qctr, 4);
        int nb_ = __builtin_amdgcn_readfirstlane(pop0);
        if (nb_ >= Nn) break;
        int nend = (nb_ + 4 < Nn) ? nb_ + 4 : Nn;

        for (int n = nb_; n < nend; ++n) {
            const int rs = row_start[n], re = row_start[n + 1];
            const int rs4 = rs >> 2;
            const int G = (re - rs) >> 2;   // all chunks full (pads zeroed)

            f32x4 acc = {0.f, 0.f, 0.f, 0.f};
            float psum = 0.f;

            if (G > 0) {
                int4 s0, s1, s2, s3;
                float4 p0, p1, p2, p3;
                f16x4 A0, A1, A2, A3, B0, B1, B2, B3;
                META(s0, p0, 0); META(s1, p1, 1); META(s2, p2, 2); META(s3, p3, 3);
                GATH(A0, A1, A2, A3, s0);
                int c = 0;
                for (; c + 4 <= G; c += 4) {
                    GATH(B0, B1, B2, B3, s1); COMP(p0, A0, A1, A2, A3); META(s0, p0, c + 4);
                    GATH(A0, A1, A2, A3, s2); COMP(p1, B0, B1, B2, B3); META(s1, p1, c + 5);
                    GATH(B0, B1, B2, B3, s3); COMP(p2, A0, A1, A2, A3); META(s2, p2, c + 6);
                    GATH(A0, A1, A2, A3, s0); COMP(p3, B0, B1, B2, B3); META(s3, p3, c + 7);
                }
                int k = G - c;
                if (k == 1) {
                    COMP(p0, A0, A1, A2, A3);
                } else if (k == 2) {
                    GATH(B0, B1, B2, B3, s1);
                    COMP(p0, A0, A1, A2, A3);
                    COMP(p1, B0, B1, B2, B3);
                } else if (k == 3) {
                    GATH(B0, B1, B2, B3, s1);
                    COMP(p0, A0, A1, A2, A3);
                    GATH(A0, A1, A2, A3, s2);
                    COMP(p1, B0, B1, B2, B3);
                    COMP(p2, A0, A1, A2, A3);
                }
            }

            // every lane of a head-group already holds the full per-head sum
            float rin = 1.f / (psum + 1e-16f);
            float v0 = acc[0] * rin + bv.x;
            float v1 = acc[1] * rin + bv.y;
            float v2 = acc[2] * rin + bv.z;
            float v3 = acc[3] * rin + bv.w;

            // LayerNorm over 256 channels (wave-wide reduce)
            float s1r = v0 + v1 + v2 + v3;
            float s2r = v0 * v0 + v1 * v1 + v2 * v2 + v3 * v3;
#pragma unroll
            for (int d = 1; d < 64; d <<= 1) {
                s1r += __shfl_xor(s1r, d, 64);
                s2r += __shfl_xor(s2r, d, 64);
            }
            float mu = s1r * (1.f / 256.f);
            float var = s2r * (1.f / 256.f) - mu * mu;
            float rstd = rsqrtf(var + 1e-5f);
            float y0 = fmaxf((v0 - mu) * rstd * gv.x + btv.x, 0.f);
            float y1 = fmaxf((v1 - mu) * rstd * gv.y + btv.y, 0.f);
            float y2 = fmaxf((v2 - mu) * rstd * gv.z + btv.z, 0.f);
            float y3 = fmaxf((v3 - mu) * rstd * gv.w + btv.w, 0.f);

            f16x4 yv;
            yv.x = (_Float16)y0; yv.y = (_Float16)y1;
            yv.z = (_Float16)y2; yv.w = (_Float16)y3;
            *(f16x4*)&yh[(size_t)n * HC + lane * 4] = yv;
        }
    }
#undef META
#undef GAT1
#undef GATH
#undef COMP
}

// ------------------------------------------------------------ FC (MFMA) -----
// out[M,10] = y[M,256](f16) @ fcWh^T(f16,[16][256]) + fcb. 4 waves x 64 rows.
__global__ __launch_bounds__(256) void fc_gemm(const unsigned short* __restrict__ yh,
                                               const unsigned short* __restrict__ fcWh,
                                               const float* __restrict__ fcb,
                                               float* __restrict__ out, int M) {
    const int lane = threadIdx.x & 63, wid = threadIdx.x >> 6;
    const int rowbase = blockIdx.x * 256 + wid * 64;
    const int fr = lane & 15, kg = lane >> 4;
    f32x4 acc[4] = {};
#pragma unroll
    for (int k0 = 0; k0 < 256; k0 += 32) {
        f16x8 bfr = *(const f16x8*)&fcWh[fr * 256 + k0 + kg * 8];
#pragma unroll
        for (int i = 0; i < 4; ++i) {
            int row = rowbase + i * 16 + fr;
            f16x8 afr = {};
            if (row < M) afr = *(const f16x8*)&yh[(size_t)row * 256 + k0 + kg * 8];
            acc[i] = __builtin_amdgcn_mfma_f32_16x16x32_f16(afr, bfr, acc[i], 0, 0, 0);
        }
    }
    if (fr < NCLS) {
        float bb = fcb[fr];
#pragma unroll
        for (int i = 0; i < 4; ++i) {
#pragma unroll
            for (int r = 0; r < 4; ++r) {
                int row = rowbase + i * 16 + kg * 4 + r;
                if (row < M) out[(size_t)row * NCLS + fr] = acc[i][r] + bb;
            }
        }
    }
}

// ---------------------------------------------------------------- launch ----
extern "C" void kernel_launch(void* const* d_in, const int* in_sizes, int n_in,
                              void* d_out, int out_size, void* d_ws, size_t ws_size,
                              hipStream_t stream) {
    const float* x    = (const float*)d_in[0];
    const int*   ei   = (const int*)d_in[1];
    const float* ew   = (const float*)d_in[2];
    const float* W    = (const float*)d_in[3];
    const float* attS = (const float*)d_in[4];
    const float* attD = (const float*)d_in[5];
    const float* attE = (const float*)d_in[6];
    const float* We   = (const float*)d_in[7];
    const float* bias = (const float*)d_in[8];
    const float* gam  = (const float*)d_in[9];
    const float* bet  = (const float*)d_in[10];
    const float* fcW  = (const float*)d_in[11];
    const float* fcb  = (const float*)d_in[12];
    float* out = (float*)d_out;

    const int Nn = in_sizes[0] / HC;       // 50000
    const int E  = in_sizes[1] / 2;        // 800000
    const int* src = ei;
    const int* dst = ei + E;
    const int nb = (Nn + 1023) / 1024;     // 49
    const int EpMax = E + 4 * Nn;          // worst-case padded slots (x4 pad)

    char* ws = (char*)d_ws;
    size_t off = 0;
    auto alloc = [&](size_t bytes) { void* p = ws + off; off = (off + bytes + 255) & ~size_t(255); return p; };
    unsigned short* xhh  = (unsigned short*)alloc((size_t)Nn * HC * 2);
    unsigned short* yh   = (unsigned short*)alloc((size_t)Nn * HC * 2);
    unsigned short* wt   = (unsigned short*)alloc((size_t)HC * HC * 2);
    unsigned short* fcWh = (unsigned short*)alloc((size_t)16 * HC * 2);
    float* a_srcb    = (float*)alloc((size_t)Nn * 4 * 4);
    float* a_dstb    = (float*)alloc((size_t)Nn * 4 * 4);
    float* cE        = (float*)alloc(256);
    int*   qctr      = (int*)  alloc(256);
    int*   row_start = (int*)  alloc((size_t)(Nn + 1) * 4);
    int*   deg       = (int*)  alloc((size_t)Nn * 4);
    int*   bsum      = (int*)  alloc((size_t)nb * 4);
    int*   rank      = (int*)  alloc((size_t)E * 4);
    int*   srcs      = (int*)  alloc((size_t)EpMax * 4 + 256);   // +slack (overshoot reads)
    float* pq        = (float*)alloc((size_t)EpMax * 16 + 1024); // [group][h][4] +slack
    (void)ws_size;

    hipMemsetAsync(deg, 0, (size_t)Nn * 4, stream);

    prep_kernel<<<273, 256, 0, stream>>>(We, attE, cE, W, wt, fcW, fcWh, qctr);

    dim3 g((Nn + 127) / 128, 2);
    gemm_mfma<<<g, 256, 0, stream>>>(x, wt, xhh, Nn);

    attn_coef<<<(Nn + 3) / 4, 256, 0, stream>>>(xhh, attS, attD, a_srcb, a_dstb, Nn);
    hist_kernel<<<(E + 255) / 256, 256, 0, stream>>>(dst, deg, rank, E);
    scan1<<<nb, 1024, 0, stream>>>(deg, row_start, bsum, Nn);
    scan23<<<nb, 1024, 0, stream>>>(row_start, bsum, deg, srcs, pq, Nn, nb);
    scatter_p<<<(E + 255) / 256, 256, 0, stream>>>(src, dst, ew, a_srcb, a_dstb, cE,
                                                   row_start, rank, srcs, pq, E);
    gat_main<<<2048, 256, 0, stream>>>(xhh, row_start, srcs, pq,
                                       bias, gam, bet, yh, qctr, Nn);
    fc_gemm<<<(Nn + 255) / 256, 256, 0, stream>>>(yh, fcWh, fcb, out, Nn);
}

// Round 8
// 208.027 us; speedup vs baseline: 1.9289x; 1.9289x over previous
//
#include <hip/hip_runtime.h>
#include <hip/hip_bf16.h>

static constexpr int HEADS = 4;
static constexpr int HID   = 64;
static constexpr int HC    = 256;   // HEADS*HID
static constexpr int NCLS  = 10;

typedef short    bf16x8 __attribute__((ext_vector_type(8)));
typedef _Float16 f16x8  __attribute__((ext_vector_type(8)));
typedef _Float16 f16x4  __attribute__((ext_vector_type(4)));
typedef float    f32x4  __attribute__((ext_vector_type(4)));

__device__ inline unsigned short f2bf(float f) {
    union { float f; unsigned u; } c; c.f = f;
    unsigned r = (c.u + 0x7fff + ((c.u >> 16) & 1)) >> 16;  // RNE
    return (unsigned short)r;
}
__device__ inline unsigned short f2h(float f) {
    _Float16 h = (_Float16)f; unsigned short u; __builtin_memcpy(&u, &h, 2); return u;
}
__device__ inline float h2f(unsigned short u) {
    _Float16 h; __builtin_memcpy(&h, &u, 2); return (float)h;
}

// ------------------------------------------------------------------ prep ----
// b=0: cE; b=1..256: Wt[n][k]=bf16(W[k][n]); b=257..272: fcWh (f16, padded)
__global__ void prep_kernel(const float* __restrict__ We, const float* __restrict__ attE,
                            float* __restrict__ cE, const float* __restrict__ W,
                            unsigned short* __restrict__ Wt, const float* __restrict__ fcW,
                            unsigned short* __restrict__ fcWh) {
    int b = blockIdx.x, t = threadIdx.x;
    if (b == 0) {
        float p = We[t] * attE[t];
#pragma unroll
        for (int d = 32; d; d >>= 1) p += __shfl_xor(p, d, 64);
        if ((t & 63) == 0) cE[t >> 6] = p;
    } else if (b <= 256) {
        int k = b - 1;
        Wt[t * 256 + k] = f2bf(W[k * 256 + t]);
    } else {
        int j = b - 257;               // 0..15
        unsigned short v = 0;
        if (j < NCLS) v = f2h(fcW[t * NCLS + j]);
        fcWh[j * 256 + t] = v;
    }
}

// ------------------------------------------------------------ MFMA GEMM -----
// XHh[M,256](f16) = X[M,256](f32) @ Wt^T (bf16 MFMA).
__global__ __launch_bounds__(256) void gemm_mfma(const float* __restrict__ X,
                                                 const unsigned short* __restrict__ Bt,
                                                 unsigned short* __restrict__ XHh, int M) {
    __shared__ alignas(16) unsigned short As[128][40];
    __shared__ alignas(16) unsigned short Bs[128][40];  // Bs[col][k]
    const int tid = threadIdx.x;
    const int lane = tid & 63, wid = tid >> 6;
    const int wr = wid >> 1, wc = wid & 1;
    const int bm = blockIdx.x * 128, bn = blockIdx.y * 128;
    const int fr = lane & 15, kg = lane >> 4;

    f32x4 acc[4][4] = {};

    for (int k0 = 0; k0 < 256; k0 += 32) {
        __syncthreads();
#pragma unroll
        for (int ss = 0; ss < 4; ++ss) {
            int idx = tid + (ss << 8);
            int row = idx >> 3, seg = idx & 7;
            int grow = bm + row;
            float4 av = make_float4(0.f, 0.f, 0.f, 0.f);
            if (grow < M) av = *(const float4*)&X[(size_t)grow * 256 + k0 + seg * 4];
            ushort4 ab = make_ushort4(f2bf(av.x), f2bf(av.y), f2bf(av.z), f2bf(av.w));
            *(ushort4*)&As[row][seg * 4] = ab;
        }
#pragma unroll
        for (int qq = 0; qq < 2; ++qq) {
            int q = tid + (qq << 8);
            int row = q >> 2, part = q & 3;
            const ushort4* bp = (const ushort4*)&Bt[(size_t)(bn + row) * 256 + k0 + part * 8];
            *(ushort4*)&Bs[row][part * 8]     = bp[0];
            *(ushort4*)&Bs[row][part * 8 + 4] = bp[1];
        }
        __syncthreads();

        bf16x8 af[4], bf[4];
#pragma unroll
        for (int i = 0; i < 4; ++i)
            af[i] = *(const bf16x8*)&As[wr * 64 + i * 16 + fr][kg * 8];
#pragma unroll
        for (int j = 0; j < 4; ++j)
            bf[j] = *(const bf16x8*)&Bs[wc * 64 + j * 16 + fr][kg * 8];
#pragma unroll
        for (int i = 0; i < 4; ++i)
#pragma unroll
            for (int j = 0; j < 4; ++j)
                acc[i][j] = __builtin_amdgcn_mfma_f32_16x16x32_bf16(af[i], bf[j], acc[i][j], 0, 0, 0);
    }

    // C/D layout: col = lane&15, row = (lane>>4)*4 + reg
#pragma unroll
    for (int i = 0; i < 4; ++i) {
#pragma unroll
        for (int j = 0; j < 4; ++j) {
            int col = bn + wc * 64 + j * 16 + fr;
#pragma unroll
            for (int r = 0; r < 4; ++r) {
                int row = bm + wr * 64 + i * 16 + kg * 4 + r;
                if (row < M) XHh[(size_t)row * 256 + col] = f2h(acc[i][j][r]);
            }
        }
    }
}

// ------------------------------------------------------- a_src / a_dst ------
__global__ __launch_bounds__(256) void attn_coef(const unsigned short* __restrict__ xhh,
                                                 const float* __restrict__ attS,
                                                 const float* __restrict__ attD,
                                                 float* __restrict__ a_src,
                                                 float* __restrict__ a_dst,
                                                 int Nn) {
    int wid = threadIdx.x >> 6, lane = threadIdx.x & 63;
    int n = blockIdx.x * 4 + wid;
    if (n >= Nn) return;
    ushort4 xv = *(const ushort4*)&xhh[(size_t)n * HC + lane * 4];
    float x0 = h2f(xv.x), x1 = h2f(xv.y), x2 = h2f(xv.z), x3 = h2f(xv.w);
    float4 sv = *(const float4*)&attS[lane * 4];
    float4 dv = *(const float4*)&attD[lane * 4];
    float ps = x0 * sv.x + x1 * sv.y + x2 * sv.z + x3 * sv.w;
    float pd = x0 * dv.x + x1 * dv.y + x2 * dv.z + x3 * dv.w;
#pragma unroll
    for (int d = 1; d < 16; d <<= 1) {
        ps += __shfl_xor(ps, d, 64);
        pd += __shfl_xor(pd, d, 64);
    }
    if ((lane & 15) == 0) {
        a_src[n * 4 + (lane >> 4)] = ps;
        a_dst[n * 4 + (lane >> 4)] = pd;
    }
}

// ------------------------------------------------------------- CSR build ----
__global__ void hist_kernel(const int* __restrict__ dst, int* __restrict__ deg,
                            int* __restrict__ rank, int E) {
    int e = blockIdx.x * 256 + threadIdx.x;
    if (e < E) rank[e] = atomicAdd(&deg[dst[e]], 1);
}

// scan of PADDED degrees (each deg rounded up to x4)
__global__ __launch_bounds__(1024) void scan1(const int* __restrict__ deg,
                                              int* __restrict__ row_start,
                                              int* __restrict__ bsum, int n) {
    __shared__ int wsum[16];
    const int tid = threadIdx.x, lane = tid & 63, wid = tid >> 6;
    int i = blockIdx.x * 1024 + tid;
    int v = (i < n) ? ((deg[i] + 3) & ~3) : 0;
    int incl = v;
#pragma unroll
    for (int d = 1; d < 64; d <<= 1) {
        int t = __shfl_up(incl, d, 64);
        if (lane >= d) incl += t;
    }
    if (lane == 63) wsum[wid] = incl;
    __syncthreads();
    if (tid < 16) {
        int w = wsum[tid];
#pragma unroll
        for (int d = 1; d < 16; d <<= 1) {
            int t = __shfl_up(w, d, 16);
            if (tid >= d) w += t;
        }
        wsum[tid] = w;
    }
    __syncthreads();
    int waveoff = wid ? wsum[wid - 1] : 0;
    if (i < n) row_start[i] = waveoff + incl - v;
    if (tid == 1023) bsum[blockIdx.x] = waveoff + incl;
}

// fused scan2+scan3 + srcs pad-slot zeroing (pads must read as src=0)
__global__ __launch_bounds__(1024) void scan23(int* __restrict__ row_start,
                                               const int* __restrict__ bsum,
                                               const int* __restrict__ deg,
                                               int* __restrict__ srcs, int n, int nb) {
    __shared__ int pref[64];
    const int tid = threadIdx.x;
    if (tid < 64) {
        int v = (tid < nb) ? bsum[tid] : 0;
#pragma unroll
        for (int d = 1; d < 64; d <<= 1) {
            int t = __shfl_up(v, d, 64);
            if (tid >= d) v += t;
        }
        pref[tid] = v;
    }
    __syncthreads();
    int add = blockIdx.x ? pref[blockIdx.x - 1] : 0;
    int i = blockIdx.x * 1024 + tid;
    if (i < n) {
        int v = row_start[i] + add;
        row_start[i] = v;
        int dn = deg[i];
        int pd = (dn + 3) & ~3;
        for (int s = dn; s < pd; ++s) srcs[v + s] = 0;   // <=3 pad slots
    }
    if (i == n) row_start[n] = pref[nb - 1];
}

// ------------------------------------------------------------ scatter{s,w} --
// Minimal CSR scatter: pos = row_start[dst] + rank. No gathers, no exp.
__global__ void scatter_sw(const int* __restrict__ src, const int* __restrict__ dst,
                           const float* __restrict__ ew,
                           const int* __restrict__ row_start, const int* __restrict__ rank,
                           int* __restrict__ srcs, float* __restrict__ ews, int E) {
    int e = blockIdx.x * 256 + threadIdx.x;
    if (e >= E) return;
    int pos = row_start[dst[e]] + rank[e];
    srcs[pos] = src[e];
    ews[pos] = ew[e];
}

// --------------------------------------------------------------- p_pass -----
// One wave per node: read its CSR segment COALESCED, gather a_src (L2),
// compute p = exp(leakyrelu(alpha)), write pq[group][h][slot] as full-line
// coalesced stores (pads written 0 -> no RMW, no pq pad pass needed).
__global__ __launch_bounds__(256) void p_pass(
    const int* __restrict__ row_start, const int* __restrict__ deg,
    const int* __restrict__ srcs, const float* __restrict__ ews,
    const float* __restrict__ a_src, const float* __restrict__ a_dst,
    const float* __restrict__ cE, float* __restrict__ pq, int Nn) {
    const int wid = threadIdx.x >> 6, lane = threadIdx.x & 63;
    const int n = blockIdx.x * 4 + wid;
    if (n >= Nn) return;
    const int rs = row_start[n];
    const int dn = deg[n];
    const int pd = (dn + 3) & ~3;
    const int slot0 = lane >> 2, h = lane & 3;
    const float adn = a_dst[n * 4 + h];
    const float ceh = cE[h];
    for (int s = slot0; s < pd; s += 16) {
        int pos = rs + s;                       // rs is x4-aligned
        float p = 0.f;
        if (s < dn) {
            int sv = srcs[pos];
            float w = ews[pos];
            float a = a_src[sv * 4 + h] + adn + ceh * w;
            a = fmaxf(a, 0.2f * a);             // leaky relu
            p = __expf(a);                      // no max-sub: |alpha| small
        }
        pq[(size_t)(pos >> 2) * 16 + h * 4 + (pos & 3)] = p;
    }
}

// ------------------------------------------------------------- main GAT -----
// One WAVE per node (R6-proven). Lane l owns channels 4l..4l+3 (head myh).
// 2-deep software pipeline, readfirstlane scalar-base gathers, exact tail.
__global__ __launch_bounds__(256) void gat_main(
    const unsigned short* __restrict__ xhh, const int* __restrict__ row_start,
    const int* __restrict__ deg, const int* __restrict__ srcs,
    const float* __restrict__ pq, const float* __restrict__ bias,
    const float* __restrict__ gamma, const float* __restrict__ beta,
    unsigned short* __restrict__ yh, int Nn) {
    const int lane = threadIdx.x & 63, wid = threadIdx.x >> 6;
    const int n = blockIdx.x * 4 + wid;
    if (n >= Nn) return;
    const int myh = lane >> 4;
    const int rs = row_start[n];
    const int dn = deg[n];
    const int nfull = dn >> 2, rem = dn & 3;
    const unsigned short* xl = xhh + (size_t)lane * 4;

    f32x4 acc = {0.f, 0.f, 0.f, 0.f};
    float psum = 0.f;

#define LOADMETA(c, S, P)                                                     \
    S = *(const int4*)&srcs[rs + (c) * 4];                                    \
    P = *(const float4*)&pq[((size_t)((rs >> 2) + (c))) * 16 + myh * 4];
#define GATHER(S, X0, X1, X2, X3)                                             \
    X0 = *(const f16x4*)(xl + (size_t)__builtin_amdgcn_readfirstlane((S).x) * HC); \
    X1 = *(const f16x4*)(xl + (size_t)__builtin_amdgcn_readfirstlane((S).y) * HC); \
    X2 = *(const f16x4*)(xl + (size_t)__builtin_amdgcn_readfirstlane((S).z) * HC); \
    X3 = *(const f16x4*)(xl + (size_t)__builtin_amdgcn_readfirstlane((S).w) * HC);
#define COMPUTE(P, X0, X1, X2, X3)                                            \
    psum += ((P).x + (P).y) + ((P).z + (P).w);                                \
    acc[0] = fmaf((P).x, (float)(X0).x, acc[0]);                              \
    acc[1] = fmaf((P).x, (float)(X0).y, acc[1]);                              \
    acc[2] = fmaf((P).x, (float)(X0).z, acc[2]);                              \
    acc[3] = fmaf((P).x, (float)(X0).w, acc[3]);                              \
    acc[0] = fmaf((P).y, (float)(X1).x, acc[0]);                              \
    acc[1] = fmaf((P).y, (float)(X1).y, acc[1]);                              \
    acc[2] = fmaf((P).y, (float)(X1).z, acc[2]);                              \
    acc[3] = fmaf((P).y, (float)(X1).w, acc[3]);                              \
    acc[0] = fmaf((P).z, (float)(X2).x, acc[0]);                              \
    acc[1] = fmaf((P).z, (float)(X2).y, acc[1]);                              \
    acc[2] = fmaf((P).z, (float)(X2).z, acc[2]);                              \
    acc[3] = fmaf((P).z, (float)(X2).w, acc[3]);                              \
    acc[0] = fmaf((P).w, (float)(X3).x, acc[0]);                              \
    acc[1] = fmaf((P).w, (float)(X3).y, acc[1]);                              \
    acc[2] = fmaf((P).w, (float)(X3).z, acc[2]);                              \
    acc[3] = fmaf((P).w, (float)(X3).w, acc[3]);

    if (nfull > 0) {
        int4 s0, sN = {0, 0, 0, 0}, s2 = {0, 0, 0, 0};
        float4 pC, pN = {0.f, 0.f, 0.f, 0.f}, p2 = {0.f, 0.f, 0.f, 0.f};
        f16x4 g0, g1, g2, g3;
        LOADMETA(0, s0, pC);
        GATHER(s0, g0, g1, g2, g3);
        if (nfull > 1) { LOADMETA(1, sN, pN); }
        for (int c = 0; c < nfull; ++c) {
            f16x4 h0, h1, h2, h3;
            if (c + 1 < nfull) { GATHER(sN, h0, h1, h2, h3); }
            if (c + 2 < nfull) { LOADMETA(c + 2, s2, p2); }
            COMPUTE(pC, g0, g1, g2, g3);
            pC = pN; pN = p2; sN = s2;
            g0 = h0; g1 = h1; g2 = h2; g3 = h3;
        }
    }
    if (rem) {
        int4 s; float4 p;
        LOADMETA(nfull, s, p);
        p.w = 0.f;
        if (rem < 3) p.z = 0.f;
        if (rem < 2) p.y = 0.f;
        int b0 = __builtin_amdgcn_readfirstlane(s.x);
        int b1 = rem > 1 ? __builtin_amdgcn_readfirstlane(s.y) : b0;
        int b2 = rem > 2 ? __builtin_amdgcn_readfirstlane(s.z) : b0;
        f16x4 x0 = *(const f16x4*)(xl + (size_t)b0 * HC);
        f16x4 x1 = *(const f16x4*)(xl + (size_t)b1 * HC);
        f16x4 x2 = *(const f16x4*)(xl + (size_t)b2 * HC);
        COMPUTE(p, x0, x1, x2, x0);     // w-slot: p.w==0
    }
#undef LOADMETA
#undef GATHER
#undef COMPUTE

    // every lane of a head-group already holds the full per-head sum
    float rin = 1.f / (psum + 1e-16f);

    float4 bv = *(const float4*)&bias[lane * 4];
    float v0 = acc[0] * rin + bv.x;
    float v1 = acc[1] * rin + bv.y;
    float v2 = acc[2] * rin + bv.z;
    float v3 = acc[3] * rin + bv.w;

    // LayerNorm over 256 channels (wave-wide reduce)
    float s1 = v0 + v1 + v2 + v3;
    float s2v = v0 * v0 + v1 * v1 + v2 * v2 + v3 * v3;
#pragma unroll
    for (int d = 1; d < 64; d <<= 1) {
        s1 += __shfl_xor(s1, d, 64);
        s2v += __shfl_xor(s2v, d, 64);
    }
    float mu = s1 * (1.f / 256.f);
    float var = s2v * (1.f / 256.f) - mu * mu;
    float rstd = rsqrtf(var + 1e-5f);
    float4 gv = *(const float4*)&gamma[lane * 4];
    float4 btv = *(const float4*)&beta[lane * 4];
    float y0 = fmaxf((v0 - mu) * rstd * gv.x + btv.x, 0.f);
    float y1 = fmaxf((v1 - mu) * rstd * gv.y + btv.y, 0.f);
    float y2 = fmaxf((v2 - mu) * rstd * gv.z + btv.z, 0.f);
    float y3 = fmaxf((v3 - mu) * rstd * gv.w + btv.w, 0.f);

    f16x4 yv;
    yv.x = (_Float16)y0; yv.y = (_Float16)y1; yv.z = (_Float16)y2; yv.w = (_Float16)y3;
    *(f16x4*)&yh[(size_t)n * HC + lane * 4] = yv;
}

// ------------------------------------------------------------ FC (MFMA) -----
// out[M,10] = y[M,256](f16) @ fcWh^T(f16,[16][256]) + fcb. 4 waves x 64 rows.
__global__ __launch_bounds__(256) void fc_gemm(const unsigned short* __restrict__ yh,
                                               const unsigned short* __restrict__ fcWh,
                                               const float* __restrict__ fcb,
                                               float* __restrict__ out, int M) {
    const int lane = threadIdx.x & 63, wid = threadIdx.x >> 6;
    const int rowbase = blockIdx.x * 256 + wid * 64;
    const int fr = lane & 15, kg = lane >> 4;
    f32x4 acc[4] = {};
#pragma unroll
    for (int k0 = 0; k0 < 256; k0 += 32) {
        f16x8 bfr = *(const f16x8*)&fcWh[fr * 256 + k0 + kg * 8];
#pragma unroll
        for (int i = 0; i < 4; ++i) {
            int row = rowbase + i * 16 + fr;
            f16x8 afr = {};
            if (row < M) afr = *(const f16x8*)&yh[(size_t)row * 256 + k0 + kg * 8];
            acc[i] = __builtin_amdgcn_mfma_f32_16x16x32_f16(afr, bfr, acc[i], 0, 0, 0);
        }
    }
    if (fr < NCLS) {
        float bb = fcb[fr];
#pragma unroll
        for (int i = 0; i < 4; ++i) {
#pragma unroll
            for (int r = 0; r < 4; ++r) {
                int row = rowbase + i * 16 + kg * 4 + r;
                if (row < M) out[(size_t)row * NCLS + fr] = acc[i][r] + bb;
            }
        }
    }
}

// ---------------------------------------------------------------- launch ----
extern "C" void kernel_launch(void* const* d_in, const int* in_sizes, int n_in,
                              void* d_out, int out_size, void* d_ws, size_t ws_size,
                              hipStream_t stream) {
    const float* x    = (const float*)d_in[0];
    const int*   ei   = (const int*)d_in[1];
    const float* ew   = (const float*)d_in[2];
    const float* W    = (const float*)d_in[3];
    const float* attS = (const float*)d_in[4];
    const float* attD = (const float*)d_in[5];
    const float* attE = (const float*)d_in[6];
    const float* We   = (const float*)d_in[7];
    const float* bias = (const float*)d_in[8];
    const float* gam  = (const float*)d_in[9];
    const float* bet  = (const float*)d_in[10];
    const float* fcW  = (const float*)d_in[11];
    const float* fcb  = (const float*)d_in[12];
    float* out = (float*)d_out;

    const int Nn = in_sizes[0] / HC;       // 50000
    const int E  = in_sizes[1] / 2;        // 800000
    const int* src = ei;
    const int* dst = ei + E;
    const int nb = (Nn + 1023) / 1024;     // 49
    const int EpMax = E + 4 * Nn;          // worst-case padded slots (x4 pad)

    char* ws = (char*)d_ws;
    size_t off = 0;
    auto alloc = [&](size_t bytes) { void* p = ws + off; off = (off + bytes + 255) & ~size_t(255); return p; };
    unsigned short* xhh  = (unsigned short*)alloc((size_t)Nn * HC * 2);
    unsigned short* yh   = (unsigned short*)alloc((size_t)Nn * HC * 2);
    unsigned short* wt   = (unsigned short*)alloc((size_t)HC * HC * 2);
    unsigned short* fcWh = (unsigned short*)alloc((size_t)16 * HC * 2);
    float* a_srcb    = (float*)alloc((size_t)Nn * 4 * 4);
    float* a_dstb    = (float*)alloc((size_t)Nn * 4 * 4);
    float* cE        = (float*)alloc(256);
    int*   row_start = (int*)  alloc((size_t)(Nn + 1) * 4);
    int*   deg       = (int*)  alloc((size_t)Nn * 4);
    int*   bsum      = (int*)  alloc((size_t)nb * 4);
    int*   rank      = (int*)  alloc((size_t)E * 4);
    int*   srcs      = (int*)  alloc((size_t)EpMax * 4 + 256);   // +slack
    float* ews       = (float*)alloc((size_t)EpMax * 4 + 256);   // +slack
    float* pq        = (float*)alloc((size_t)EpMax * 16 + 1024); // [group][h][4] +slack
    (void)ws_size;

    hipMemsetAsync(deg, 0, (size_t)Nn * 4, stream);

    prep_kernel<<<273, 256, 0, stream>>>(We, attE, cE, W, wt, fcW, fcWh);

    dim3 g((Nn + 127) / 128, 2);
    gemm_mfma<<<g, 256, 0, stream>>>(x, wt, xhh, Nn);

    attn_coef<<<(Nn + 3) / 4, 256, 0, stream>>>(xhh, attS, attD, a_srcb, a_dstb, Nn);
    hist_kernel<<<(E + 255) / 256, 256, 0, stream>>>(dst, deg, rank, E);
    scan1<<<nb, 1024, 0, stream>>>(deg, row_start, bsum, Nn);
    scan23<<<nb, 1024, 0, stream>>>(row_start, bsum, deg, srcs, Nn, nb);
    scatter_sw<<<(E + 255) / 256, 256, 0, stream>>>(src, dst, ew, row_start, rank,
                                                    srcs, ews, E);
    p_pass<<<(Nn + 3) / 4, 256, 0, stream>>>(row_start, deg, srcs, ews,
                                             a_srcb, a_dstb, cE, pq, Nn);
    gat_main<<<(Nn + 3) / 4, 256, 0, stream>>>(xhh, row_start, deg, srcs, pq,
                                               bias, gam, bet, yh, Nn);
    fc_gemm<<<(Nn + 255) / 256, 256, 0, stream>>>(yh, fcWh, fcb, out, Nn);
}

// Round 9
// 198.776 us; speedup vs baseline: 2.0186x; 1.0465x over previous
//
#include <hip/hip_runtime.h>
#include <hip/hip_bf16.h>

static constexpr int HEADS = 4;
static constexpr int HID   = 64;
static constexpr int HC    = 256;   // HEADS*HID
static constexpr int NCLS  = 10;

typedef short    bf16x8 __attribute__((ext_vector_type(8)));
typedef _Float16 f16x8  __attribute__((ext_vector_type(8)));
typedef _Float16 f16x4  __attribute__((ext_vector_type(4)));
typedef float    f32x4  __attribute__((ext_vector_type(4)));

__device__ inline unsigned short f2bf(float f) {
    union { float f; unsigned u; } c; c.f = f;
    unsigned r = (c.u + 0x7fff + ((c.u >> 16) & 1)) >> 16;  // RNE
    return (unsigned short)r;
}
__device__ inline unsigned short f2h(float f) {
    _Float16 h = (_Float16)f; unsigned short u; __builtin_memcpy(&u, &h, 2); return u;
}
__device__ inline float h2f(unsigned short u) {
    _Float16 h; __builtin_memcpy(&h, &u, 2); return (float)h;
}

// ------------------------------------------------------------------ prep ----
// b=0: cE; b=1..256: Wt; b=257..272: fcWh; b>=273: zero deg (fused memset)
__global__ void prep_kernel(const float* __restrict__ We, const float* __restrict__ attE,
                            float* __restrict__ cE, const float* __restrict__ W,
                            unsigned short* __restrict__ Wt, const float* __restrict__ fcW,
                            unsigned short* __restrict__ fcWh, int* __restrict__ deg,
                            int Nn) {
    int b = blockIdx.x, t = threadIdx.x;
    if (b == 0) {
        float p = We[t] * attE[t];
#pragma unroll
        for (int d = 32; d; d >>= 1) p += __shfl_xor(p, d, 64);
        if ((t & 63) == 0) cE[t >> 6] = p;
    } else if (b <= 256) {
        int k = b - 1;
        Wt[t * 256 + k] = f2bf(W[k * 256 + t]);
    } else if (b <= 272) {
        int j = b - 257;               // 0..15
        unsigned short v = 0;
        if (j < NCLS) v = f2h(fcW[t * NCLS + j]);
        fcWh[j * 256 + t] = v;
    } else {
        int i = (b - 273) * 256 + t;
        if (i < Nn) deg[i] = 0;
    }
}

// ------------------------------------------------------------ MFMA GEMM -----
// XHh[M,256](f16) = X[M,256](f32) @ Wt^T (bf16 MFMA).
__global__ __launch_bounds__(256) void gemm_mfma(const float* __restrict__ X,
                                                 const unsigned short* __restrict__ Bt,
                                                 unsigned short* __restrict__ XHh, int M) {
    __shared__ alignas(16) unsigned short As[128][40];
    __shared__ alignas(16) unsigned short Bs[128][40];  // Bs[col][k]
    const int tid = threadIdx.x;
    const int lane = tid & 63, wid = tid >> 6;
    const int wr = wid >> 1, wc = wid & 1;
    const int bm = blockIdx.x * 128, bn = blockIdx.y * 128;
    const int fr = lane & 15, kg = lane >> 4;

    f32x4 acc[4][4] = {};

    for (int k0 = 0; k0 < 256; k0 += 32) {
        __syncthreads();
#pragma unroll
        for (int ss = 0; ss < 4; ++ss) {
            int idx = tid + (ss << 8);
            int row = idx >> 3, seg = idx & 7;
            int grow = bm + row;
            float4 av = make_float4(0.f, 0.f, 0.f, 0.f);
            if (grow < M) av = *(const float4*)&X[(size_t)grow * 256 + k0 + seg * 4];
            ushort4 ab = make_ushort4(f2bf(av.x), f2bf(av.y), f2bf(av.z), f2bf(av.w));
            *(ushort4*)&As[row][seg * 4] = ab;
        }
#pragma unroll
        for (int qq = 0; qq < 2; ++qq) {
            int q = tid + (qq << 8);
            int row = q >> 2, part = q & 3;
            const ushort4* bp = (const ushort4*)&Bt[(size_t)(bn + row) * 256 + k0 + part * 8];
            *(ushort4*)&Bs[row][part * 8]     = bp[0];
            *(ushort4*)&Bs[row][part * 8 + 4] = bp[1];
        }
        __syncthreads();

        bf16x8 af[4], bf[4];
#pragma unroll
        for (int i = 0; i < 4; ++i)
            af[i] = *(const bf16x8*)&As[wr * 64 + i * 16 + fr][kg * 8];
#pragma unroll
        for (int j = 0; j < 4; ++j)
            bf[j] = *(const bf16x8*)&Bs[wc * 64 + j * 16 + fr][kg * 8];
#pragma unroll
        for (int i = 0; i < 4; ++i)
#pragma unroll
            for (int j = 0; j < 4; ++j)
                acc[i][j] = __builtin_amdgcn_mfma_f32_16x16x32_bf16(af[i], bf[j], acc[i][j], 0, 0, 0);
    }

    // C/D layout: col = lane&15, row = (lane>>4)*4 + reg
#pragma unroll
    for (int i = 0; i < 4; ++i) {
#pragma unroll
        for (int j = 0; j < 4; ++j) {
            int col = bn + wc * 64 + j * 16 + fr;
#pragma unroll
            for (int r = 0; r < 4; ++r) {
                int row = bm + wr * 64 + i * 16 + kg * 4 + r;
                if (row < M) XHh[(size_t)row * 256 + col] = f2h(acc[i][j][r]);
            }
        }
    }
}

// ------------------------------------------------------- a_src / a_dst ------
__global__ __launch_bounds__(256) void attn_coef(const unsigned short* __restrict__ xhh,
                                                 const float* __restrict__ attS,
                                                 const float* __restrict__ attD,
                                                 float* __restrict__ a_src,
                                                 float* __restrict__ a_dst,
                                                 int Nn) {
    int wid = threadIdx.x >> 6, lane = threadIdx.x & 63;
    int n = blockIdx.x * 4 + wid;
    if (n >= Nn) return;
    ushort4 xv = *(const ushort4*)&xhh[(size_t)n * HC + lane * 4];
    float x0 = h2f(xv.x), x1 = h2f(xv.y), x2 = h2f(xv.z), x3 = h2f(xv.w);
    float4 sv = *(const float4*)&attS[lane * 4];
    float4 dv = *(const float4*)&attD[lane * 4];
    float ps = x0 * sv.x + x1 * sv.y + x2 * sv.z + x3 * sv.w;
    float pd = x0 * dv.x + x1 * dv.y + x2 * dv.z + x3 * dv.w;
#pragma unroll
    for (int d = 1; d < 16; d <<= 1) {
        ps += __shfl_xor(ps, d, 64);
        pd += __shfl_xor(pd, d, 64);
    }
    if ((lane & 15) == 0) {
        a_src[n * 4 + (lane >> 4)] = ps;
        a_dst[n * 4 + (lane >> 4)] = pd;
    }
}

// ------------------------------------------------------------- CSR build ----
__global__ void hist_kernel(const int* __restrict__ dst, int* __restrict__ deg,
                            int* __restrict__ rank, int E) {
    int e = blockIdx.x * 256 + threadIdx.x;
    if (e < E) rank[e] = atomicAdd(&deg[dst[e]], 1);
}

// scan of PADDED degrees (each deg rounded up to x4)
__global__ __launch_bounds__(1024) void scan1(const int* __restrict__ deg,
                                              int* __restrict__ row_start,
                                              int* __restrict__ bsum, int n) {
    __shared__ int wsum[16];
    const int tid = threadIdx.x, lane = tid & 63, wid = tid >> 6;
    int i = blockIdx.x * 1024 + tid;
    int v = (i < n) ? ((deg[i] + 3) & ~3) : 0;
    int incl = v;
#pragma unroll
    for (int d = 1; d < 64; d <<= 1) {
        int t = __shfl_up(incl, d, 64);
        if (lane >= d) incl += t;
    }
    if (lane == 63) wsum[wid] = incl;
    __syncthreads();
    if (tid < 16) {
        int w = wsum[tid];
#pragma unroll
        for (int d = 1; d < 16; d <<= 1) {
            int t = __shfl_up(w, d, 16);
            if (tid >= d) w += t;
        }
        wsum[tid] = w;
    }
    __syncthreads();
    int waveoff = wid ? wsum[wid - 1] : 0;
    if (i < n) row_start[i] = waveoff + incl - v;
    if (tid == 1023) bsum[blockIdx.x] = waveoff + incl;
}

// fused scan2+scan3 + combined-record pad zeroing
__global__ __launch_bounds__(1024) void scan23(int* __restrict__ row_start,
                                               const int* __restrict__ bsum,
                                               const int* __restrict__ deg,
                                               int2* __restrict__ sew, int n, int nb) {
    __shared__ int pref[64];
    const int tid = threadIdx.x;
    if (tid < 64) {
        int v = (tid < nb) ? bsum[tid] : 0;
#pragma unroll
        for (int d = 1; d < 64; d <<= 1) {
            int t = __shfl_up(v, d, 64);
            if (tid >= d) v += t;
        }
        pref[tid] = v;
    }
    __syncthreads();
    int add = blockIdx.x ? pref[blockIdx.x - 1] : 0;
    int i = blockIdx.x * 1024 + tid;
    if (i < n) {
        int v = row_start[i] + add;
        row_start[i] = v;
        int dn = deg[i];
        int pd = (dn + 3) & ~3;
        for (int s = dn; s < pd; ++s) sew[v + s] = make_int2(0, 0);  // <=3 pads
    }
    if (i == n) row_start[n] = pref[nb - 1];
}

// ------------------------------------------------------------ scatter -------
// Single 8B combined record per edge -> ONE cacheline touch per edge.
__global__ void scatter_sw(const int* __restrict__ src, const int* __restrict__ dst,
                           const float* __restrict__ ew,
                           const int* __restrict__ row_start, const int* __restrict__ rank,
                           int2* __restrict__ sew, int E) {
    int e = blockIdx.x * 256 + threadIdx.x;
    if (e >= E) return;
    int pos = row_start[dst[e]] + rank[e];
    sew[pos] = make_int2(src[e], __float_as_int(ew[e]));
}

// --------------------------------------------------------------- p_pass -----
// One wave per node: read combined records COALESCED, gather a_src (L2),
// compute p = exp(leakyrelu(alpha)); emit srcs (int) + pq, both coalesced.
__global__ __launch_bounds__(256) void p_pass(
    const int* __restrict__ row_start, const int* __restrict__ deg,
    const int2* __restrict__ sew, const float* __restrict__ a_src,
    const float* __restrict__ a_dst, const float* __restrict__ cE,
    int* __restrict__ srcs, float* __restrict__ pq, int Nn) {
    const int wid = threadIdx.x >> 6, lane = threadIdx.x & 63;
    const int n = blockIdx.x * 4 + wid;
    if (n >= Nn) return;
    const int rs = row_start[n];
    const int dn = deg[n];
    const int pd = (dn + 3) & ~3;
    const int slot0 = lane >> 2, h = lane & 3;
    const float adn = a_dst[n * 4 + h];
    const float ceh = cE[h];
    for (int s = slot0; s < pd; s += 16) {
        int pos = rs + s;                       // rs is x4-aligned
        int2 r = sew[pos];                      // pads are {0,0}
        float p = 0.f;
        if (s < dn) {
            float a = a_src[r.x * 4 + h] + adn + ceh * __int_as_float(r.y);
            a = fmaxf(a, 0.2f * a);             // leaky relu
            p = __expf(a);                      // no max-sub: |alpha| small
        }
        if (h == 0) srcs[pos] = r.x;
        pq[(size_t)(pos >> 2) * 16 + h * 4 + (pos & 3)] = p;
    }
}

// ------------------------------------------------------------- main GAT -----
// TWO waves per node (even/odd chunks, stride 2), 2-deep pipeline each,
// LDS merge + single barrier, epilogue on the even wave. All chunks full
// (srcs/pq pads zeroed upstream). Lane l owns channels 4l..4l+3.
__global__ __launch_bounds__(256) void gat_main(
    const unsigned short* __restrict__ xhh, const int* __restrict__ row_start,
    const int* __restrict__ srcs, const float* __restrict__ pq,
    const float* __restrict__ bias, const float* __restrict__ gamma,
    const float* __restrict__ beta, unsigned short* __restrict__ yh, int Nn) {
    __shared__ alignas(16) f32x4 s_acc[2][64];
    __shared__ float s_ps[2][64];

    const int lane = threadIdx.x & 63, wid = threadIdx.x >> 6;
    const int nslot = wid >> 1, sub = wid & 1;
    const int n = blockIdx.x * 2 + nslot;
    const int myh = lane >> 4;
    const unsigned short* xl = xhh + (size_t)lane * 4;

    f32x4 acc = {0.f, 0.f, 0.f, 0.f};
    float psum = 0.f;

    if (n < Nn) {
        const int rs = row_start[n], re = row_start[n + 1];
        const int rs4 = rs >> 2;
        const int G = (re - rs) >> 2;           // all chunks full
        const int myG = (G - sub + 1) >> 1;     // this wave's chunk count

#define LOADMETA(c, S, P)                                                     \
    S = *(const int4*)&srcs[(rs4 + (c)) * 4];                                 \
    P = *(const float4*)&pq[((size_t)(rs4 + (c))) * 16 + myh * 4];
#define GATHER(S, X0, X1, X2, X3)                                             \
    X0 = *(const f16x4*)(xl + (size_t)__builtin_amdgcn_readfirstlane((S).x) * HC); \
    X1 = *(const f16x4*)(xl + (size_t)__builtin_amdgcn_readfirstlane((S).y) * HC); \
    X2 = *(const f16x4*)(xl + (size_t)__builtin_amdgcn_readfirstlane((S).z) * HC); \
    X3 = *(const f16x4*)(xl + (size_t)__builtin_amdgcn_readfirstlane((S).w) * HC);
#define COMPUTE(P, X0, X1, X2, X3)                                            \
    psum += ((P).x + (P).y) + ((P).z + (P).w);                                \
    acc[0] = fmaf((P).x, (float)(X0).x, acc[0]);                              \
    acc[1] = fmaf((P).x, (float)(X0).y, acc[1]);                              \
    acc[2] = fmaf((P).x, (float)(X0).z, acc[2]);                              \
    acc[3] = fmaf((P).x, (float)(X0).w, acc[3]);                              \
    acc[0] = fmaf((P).y, (float)(X1).x, acc[0]);                              \
    acc[1] = fmaf((P).y, (float)(X1).y, acc[1]);                              \
    acc[2] = fmaf((P).y, (float)(X1).z, acc[2]);                              \
    acc[3] = fmaf((P).y, (float)(X1).w, acc[3]);                              \
    acc[0] = fmaf((P).z, (float)(X2).x, acc[0]);                              \
    acc[1] = fmaf((P).z, (float)(X2).y, acc[1]);                              \
    acc[2] = fmaf((P).z, (float)(X2).z, acc[2]);                              \
    acc[3] = fmaf((P).z, (float)(X2).w, acc[3]);                              \
    acc[0] = fmaf((P).w, (float)(X3).x, acc[0]);                              \
    acc[1] = fmaf((P).w, (float)(X3).y, acc[1]);                              \
    acc[2] = fmaf((P).w, (float)(X3).z, acc[2]);                              \
    acc[3] = fmaf((P).w, (float)(X3).w, acc[3]);

        if (myG > 0) {
            int4 s0, sN = {0, 0, 0, 0}, s2 = {0, 0, 0, 0};
            float4 pC, pN = {0.f, 0.f, 0.f, 0.f}, p2 = {0.f, 0.f, 0.f, 0.f};
            f16x4 g0, g1, g2, g3;
            LOADMETA(sub, s0, pC);
            GATHER(s0, g0, g1, g2, g3);
            if (myG > 1) { LOADMETA(sub + 2, sN, pN); }
            for (int k = 0; k < myG; ++k) {
                f16x4 h0, h1, h2, h3;
                if (k + 1 < myG) { GATHER(sN, h0, h1, h2, h3); }
                if (k + 2 < myG) { LOADMETA(sub + 2 * (k + 2), s2, p2); }
                COMPUTE(pC, g0, g1, g2, g3);
                pC = pN; pN = p2; sN = s2;
                g0 = h0; g1 = h1; g2 = h2; g3 = h3;
            }
        }
#undef LOADMETA
#undef GATHER
#undef COMPUTE
    }

    // merge the odd wave into the even wave
    if (sub == 1) { s_acc[nslot][lane] = acc; s_ps[nslot][lane] = psum; }
    __syncthreads();
    if (sub == 1 || n >= Nn) return;
    f32x4 oacc = s_acc[nslot][lane];
    acc[0] += oacc[0]; acc[1] += oacc[1]; acc[2] += oacc[2]; acc[3] += oacc[3];
    psum += s_ps[nslot][lane];

    // every lane of a head-group holds the full per-head sum
    float rin = 1.f / (psum + 1e-16f);

    float4 bv = *(const float4*)&bias[lane * 4];
    float v0 = acc[0] * rin + bv.x;
    float v1 = acc[1] * rin + bv.y;
    float v2 = acc[2] * rin + bv.z;
    float v3 = acc[3] * rin + bv.w;

    // LayerNorm over 256 channels (wave-wide reduce)
    float s1 = v0 + v1 + v2 + v3;
    float s2v = v0 * v0 + v1 * v1 + v2 * v2 + v3 * v3;
#pragma unroll
    for (int d = 1; d < 64; d <<= 1) {
        s1 += __shfl_xor(s1, d, 64);
        s2v += __shfl_xor(s2v, d, 64);
    }
    float mu = s1 * (1.f / 256.f);
    float var = s2v * (1.f / 256.f) - mu * mu;
    float rstd = rsqrtf(var + 1e-5f);
    float4 gv = *(const float4*)&gamma[lane * 4];
    float4 btv = *(const float4*)&beta[lane * 4];
    float y0 = fmaxf((v0 - mu) * rstd * gv.x + btv.x, 0.f);
    float y1 = fmaxf((v1 - mu) * rstd * gv.y + btv.y, 0.f);
    float y2 = fmaxf((v2 - mu) * rstd * gv.z + btv.z, 0.f);
    float y3 = fmaxf((v3 - mu) * rstd * gv.w + btv.w, 0.f);

    f16x4 yv;
    yv.x = (_Float16)y0; yv.y = (_Float16)y1; yv.z = (_Float16)y2; yv.w = (_Float16)y3;
    *(f16x4*)&yh[(size_t)n * HC + lane * 4] = yv;
}

// ------------------------------------------------------------ FC (MFMA) -----
// out[M,10] = y[M,256](f16) @ fcWh^T(f16,[16][256]) + fcb. 4 waves x 64 rows.
__global__ __launch_bounds__(256) void fc_gemm(const unsigned short* __restrict__ yh,
                                               const unsigned short* __restrict__ fcWh,
                                               const float* __restrict__ fcb,
                                               float* __restrict__ out, int M) {
    const int lane = threadIdx.x & 63, wid = threadIdx.x >> 6;
    const int rowbase = blockIdx.x * 256 + wid * 64;
    const int fr = lane & 15, kg = lane >> 4;
    f32x4 acc[4] = {};
#pragma unroll
    for (int k0 = 0; k0 < 256; k0 += 32) {
        f16x8 bfr = *(const f16x8*)&fcWh[fr * 256 + k0 + kg * 8];
#pragma unroll
        for (int i = 0; i < 4; ++i) {
            int row = rowbase + i * 16 + fr;
            f16x8 afr = {};
            if (row < M) afr = *(const f16x8*)&yh[(size_t)row * 256 + k0 + kg * 8];
            acc[i] = __builtin_amdgcn_mfma_f32_16x16x32_f16(afr, bfr, acc[i], 0, 0, 0);
        }
    }
    if (fr < NCLS) {
        float bb = fcb[fr];
#pragma unroll
        for (int i = 0; i < 4; ++i) {
#pragma unroll
            for (int r = 0; r < 4; ++r) {
                int row = rowbase + i * 16 + kg * 4 + r;
                if (row < M) out[(size_t)row * NCLS + fr] = acc[i][r] + bb;
            }
        }
    }
}

// ---------------------------------------------------------------- launch ----
extern "C" void kernel_launch(void* const* d_in, const int* in_sizes, int n_in,
                              void* d_out, int out_size, void* d_ws, size_t ws_size,
                              hipStream_t stream) {
    const float* x    = (const float*)d_in[0];
    const int*   ei   = (const int*)d_in[1];
    const float* ew   = (const float*)d_in[2];
    const float* W    = (const float*)d_in[3];
    const float* attS = (const float*)d_in[4];
    const float* attD = (const float*)d_in[5];
    const float* attE = (const float*)d_in[6];
    const float* We   = (const float*)d_in[7];
    const float* bias = (const float*)d_in[8];
    const float* gam  = (const float*)d_in[9];
    const float* bet  = (const float*)d_in[10];
    const float* fcW  = (const float*)d_in[11];
    const float* fcb  = (const float*)d_in[12];
    float* out = (float*)d_out;

    const int Nn = in_sizes[0] / HC;       // 50000
    const int E  = in_sizes[1] / 2;        // 800000
    const int* src = ei;
    const int* dst = ei + E;
    const int nb = (Nn + 1023) / 1024;     // 49
    const int EpMax = E + 4 * Nn;          // worst-case padded slots (x4 pad)

    char* ws = (char*)d_ws;
    size_t off = 0;
    auto alloc = [&](size_t bytes) { void* p = ws + off; off = (off + bytes + 255) & ~size_t(255); return p; };
    unsigned short* xhh  = (unsigned short*)alloc((size_t)Nn * HC * 2);
    unsigned short* yh   = (unsigned short*)alloc((size_t)Nn * HC * 2);
    unsigned short* wt   = (unsigned short*)alloc((size_t)HC * HC * 2);
    unsigned short* fcWh = (unsigned short*)alloc((size_t)16 * HC * 2);
    float* a_srcb    = (float*)alloc((size_t)Nn * 4 * 4);
    float* a_dstb    = (float*)alloc((size_t)Nn * 4 * 4);
    float* cE        = (float*)alloc(256);
    int*   row_start = (int*)  alloc((size_t)(Nn + 1) * 4);
    int*   deg       = (int*)  alloc((size_t)Nn * 4);
    int*   bsum      = (int*)  alloc((size_t)nb * 4);
    int*   rank      = (int*)  alloc((size_t)E * 4);
    int2*  sew       = (int2*) alloc((size_t)EpMax * 8 + 256);   // {src, ew} +slack
    int*   srcs      = (int*)  alloc((size_t)EpMax * 4 + 256);   // +slack
    float* pq        = (float*)alloc((size_t)EpMax * 16 + 1024); // [group][h][4] +slack
    (void)ws_size;

    prep_kernel<<<273 + (Nn + 255) / 256, 256, 0, stream>>>(We, attE, cE, W, wt,
                                                            fcW, fcWh, deg, Nn);

    dim3 g((Nn + 127) / 128, 2);
    gemm_mfma<<<g, 256, 0, stream>>>(x, wt, xhh, Nn);

    attn_coef<<<(Nn + 3) / 4, 256, 0, stream>>>(xhh, attS, attD, a_srcb, a_dstb, Nn);
    hist_kernel<<<(E + 255) / 256, 256, 0, stream>>>(dst, deg, rank, E);
    scan1<<<nb, 1024, 0, stream>>>(deg, row_start, bsum, Nn);
    scan23<<<nb, 1024, 0, stream>>>(row_start, bsum, deg, sew, Nn, nb);
    scatter_sw<<<(E + 255) / 256, 256, 0, stream>>>(src, dst, ew, row_start, rank,
                                                    sew, E);
    p_pass<<<(Nn + 3) / 4, 256, 0, stream>>>(row_start, deg, sew,
                                             a_srcb, a_dstb, cE, srcs, pq, Nn);
    gat_main<<<(Nn + 1) / 2, 256, 0, stream>>>(xhh, row_start, srcs, pq,
                                               bias, gam, bet, yh, Nn);
    fc_gemm<<<(Nn + 255) / 256, 256, 0, stream>>>(yh, fcWh, fcb, out, Nn);
}